// Round 3
// baseline (4423.079 us; speedup 1.0000x reference)
//
#include <hip/hip_runtime.h>

typedef unsigned short u16;
typedef unsigned int u32;
typedef short bf16x8 __attribute__((ext_vector_type(8)));
typedef float f32x4 __attribute__((ext_vector_type(4)));

#define NB 128
#define NL 400
#define NT 30
#define NE 300
#define KE 320     // padded emb K
#define NHE 512
#define NHD 512
#define NA 512
#define NV 20000
#define NVP 20096
#define K1 1024    // [s, ctx]
#define N1 2048    // W1 rows: rz(1024) | hn(512) | in_ctx(512)
#define NW 2048    // Wemb rows: Wih_emb(1536) | readW_emb(512)
#define OUTW (NV+NL)

static __device__ __forceinline__ u16 f2b(float x){ u32 u=__float_as_uint(x); u += 0x7FFFu + ((u>>16)&1u); return (u16)(u>>16); }
static __device__ __forceinline__ float b2f(u16 h){ return __uint_as_float(((u32)h)<<16); }
static __device__ __forceinline__ float fsig(float x){ return 1.f/(1.f+__expf(-x)); }
static __device__ __forceinline__ float ftanh(float x){ return 1.f - 2.f/(__expf(2.f*x)+1.f); }

static __device__ __forceinline__ void gll16(const u16* g, u16* l){
  __builtin_amdgcn_global_load_lds((const __attribute__((address_space(1))) void*)g,
                                   (__attribute__((address_space(3))) void*)l, 16, 0, 0);
}

// 128x128 output tile, A[M,K] x B[N,K] (both row-major bf16), f32 accum.
static __device__ __forceinline__ void gemm_core(const u16* A, int lda, const u16* Bm, int ldb,
                                                 int K, u16* lsA, u16* lsB, f32x4 (&acc)[4][4]){
  const int tid = threadIdx.x;
  const int wave = tid>>6, lane = tid&63;
  const int srow = lane>>2, sko = (lane&3)*8;
  const int wm = wave>>1, wn = wave&1;
#pragma unroll
  for (int i=0;i<4;i++)
#pragma unroll
    for (int j=0;j<4;j++)
#pragma unroll
      for (int q=0;q<4;q++) acc[i][j][q] = 0.f;
  for (int kt=0; kt<K; kt+=32){
#pragma unroll
    for (int i=0;i<2;i++){
      const int c = wave*2+i;
      const int row = c*16 + srow;
      gll16(A + (size_t)row*lda + kt + sko, lsA + c*512);
      gll16(Bm + (size_t)row*ldb + kt + sko, lsB + c*512);
    }
    __syncthreads();
    bf16x8 aF[4], bF[4];
#pragma unroll
    for (int mi=0;mi<4;mi++) aF[mi] = *(const bf16x8*)(lsA + (wm*64+mi*16+(lane&15))*32 + (lane>>4)*8);
#pragma unroll
    for (int nj=0;nj<4;nj++) bF[nj] = *(const bf16x8*)(lsB + (wn*64+nj*16+(lane&15))*32 + (lane>>4)*8);
#pragma unroll
    for (int mi=0;mi<4;mi++)
#pragma unroll
      for (int nj=0;nj<4;nj++)
        acc[mi][nj] = __builtin_amdgcn_mfma_f32_16x16x32_bf16(aF[mi], bF[nj], acc[mi][nj], 0,0,0);
    __syncthreads();
  }
}

// ---------------- setup kernels ----------------

__global__ __launch_bounds__(256) void k_conv_flat(const float* __restrict__ s, u16* __restrict__ d, long n){
  long i = (long)blockIdx.x*256 + threadIdx.x;
  const long st = (long)gridDim.x*256;
  for (; i<n; i+=st) d[i] = f2b(s[i]);
}

__global__ __launch_bounds__(256) void k_convpad(const float* __restrict__ s, u16* __restrict__ d,
                                                 int srows, int sk, int dk, long total){
  long i = (long)blockIdx.x*256 + threadIdx.x;
  const long st = (long)gridDim.x*256;
  for (; i<total; i+=st){
    int r = (int)(i / dk), k = (int)(i - (long)r*dk);
    d[i] = (r < srows && k < sk) ? f2b(s[(size_t)r*sk + k]) : (u16)0;
  }
}

// encT[b][j][l] bf16 from enc[b][l][j] f32. grid (16, 128), 512 thr
__global__ __launch_bounds__(512) void k_transpose(const float* __restrict__ enc, u16* __restrict__ encT){
  const int b = blockIdx.y, jt = blockIdx.x;
  __shared__ float tile[16][33];
  const int tid = threadIdx.x;
  for (int lt=0; lt<25; lt++){
    {
      int l = lt*16 + (tid>>5), j = jt*32 + (tid&31);
      tile[tid>>5][tid&31] = enc[((size_t)b*NL + l)*512 + j];
    }
    __syncthreads();
    {
      int jw = tid>>4, lw = tid&15;
      encT[((size_t)b*512 + jt*32 + jw)*NL + lt*16 + lw] = f2b(tile[lw][jw]);
    }
    __syncthreads();
  }
}

// W1[2048][1024]: rows 0..1024: [Whh_rz | Wih_ctx_rz]; 1024..1536: [Whh_n | 0]; 1536..2048: [0 | Wih_ctx_n]
__global__ __launch_bounds__(256) void k_build_w1(const float* __restrict__ Whh, const float* __restrict__ Wih, u16* __restrict__ d){
  int idx = blockIdx.x*256 + threadIdx.x;
  if (idx >= N1*K1) return;
  int n = idx >> 10, k = idx & 1023;
  float v = 0.f;
  if (n < 1024)       v = (k<512) ? Whh[(size_t)n*512 + k] : Wih[(size_t)n*812 + 300 + (k-512)];
  else if (n < 1536)  v = (k<512) ? Whh[(size_t)n*512 + k] : 0.f;
  else                v = (k<512) ? 0.f : Wih[(size_t)(n-512)*812 + 300 + (k-512)];
  d[idx] = f2b(v);
}

// W2[512][1024]: [read_W_s (cols 812..1324) | read_W_ctx (cols 300..812)]
__global__ __launch_bounds__(256) void k_build_w2(const float* __restrict__ Wr, u16* __restrict__ d){
  int idx = blockIdx.x*256 + threadIdx.x;
  if (idx >= 512*K1) return;
  int r = idx >> 10, k = idx & 1023;
  float v = (k<512) ? Wr[(size_t)r*1324 + 812 + k] : Wr[(size_t)r*1324 + 300 + (k-512)];
  d[idx] = f2b(v);
}

// Wemb[2048][320]: rows 0..1536 = Wih[:,0:300]; rows 1536..2048 = read_W[:,0:300]; k>=300 pad 0
__global__ __launch_bounds__(256) void k_build_wemb(const float* __restrict__ Wih, const float* __restrict__ Wr, u16* __restrict__ d){
  int idx = blockIdx.x*256 + threadIdx.x;
  if (idx >= NW*KE) return;
  int n = idx / KE, k = idx - n*KE;
  float v = 0.f;
  if (k < NE) v = (n < 1536) ? Wih[(size_t)n*812 + k] : Wr[(size_t)(n-1536)*1324 + k];
  d[idx] = f2b(v);
}

// Xemb[30*128][320]: word_t = t==0 ? SOS : clip(tgt[b][t-1])
__global__ __launch_bounds__(256) void k_build_xemb(const int* __restrict__ tgt, const float* __restrict__ embed, u16* __restrict__ d){
  int idx = blockIdx.x*256 + threadIdx.x;
  if (idx >= NT*NB*KE) return;
  int row = idx / KE, k = idx - row*KE;
  int t = row >> 7, b = row & 127;
  u16 hv = 0;
  if (k < NE){
    int w = 2;
    if (t > 0){ w = tgt[b*NT + t-1]; if ((u32)w >= (u32)NV) w = 1; }
    hv = f2b(embed[(size_t)w*NE + k]);
  }
  d[idx] = hv;
}

__global__ __launch_bounds__(256) void k_init(const float* __restrict__ s_in, float* __restrict__ sbuf0, u16* __restrict__ x1){
  int idx = blockIdx.x*256 + threadIdx.x;
  if (idx < 65536){
    int b = idx>>9, j = idx&511;
    float v = s_in[idx];
    sbuf0[idx] = v;
    x1[(size_t)b*K1 + j] = f2b(v);
  } else if (idx < 131072){
    int k = idx - 65536;
    int b = k>>9, j = k&511;
    x1[(size_t)b*K1 + 512 + j] = 0;
  }
}

// enc_proj = enc @ att_Wh^T, bf16. grid (4,400)
__global__ __launch_bounds__(256) void k_encproj(const u16* __restrict__ A, const u16* __restrict__ Bw, u16* __restrict__ C){
  __shared__ __align__(16) u16 lsA[4096], lsB[4096];
  const int n0 = blockIdx.x*128, m0 = blockIdx.y*128;
  f32x4 acc[4][4];
  gemm_core(A + (size_t)m0*512, 512, Bw + (size_t)n0*512, 512, 512, lsA, lsB, acc);
  const int tid=threadIdx.x, wave=tid>>6, lane=tid&63, wm=wave>>1, wn=wave&1;
#pragma unroll
  for (int mi=0;mi<4;mi++)
#pragma unroll
    for (int nj=0;nj<4;nj++)
#pragma unroll
      for (int q=0;q<4;q++){
        int r = m0 + wm*64 + mi*16 + (lane>>4)*4 + q;
        int c = n0 + wn*64 + nj*16 + (lane&15);
        C[(size_t)r*512 + c] = f2b(acc[mi][nj][q]);
      }
}

// gre = Xemb @ Wemb^T, f32 [3840][2048]. grid (16,30)
__global__ __launch_bounds__(256) void k_gemm_emb(const u16* __restrict__ Xe, const u16* __restrict__ We, float* __restrict__ gre){
  __shared__ __align__(16) u16 lsA[4096], lsB[4096];
  const int n0 = blockIdx.x*128, m0 = blockIdx.y*128;
  f32x4 acc[4][4];
  gemm_core(Xe + (size_t)m0*KE, KE, We + (size_t)n0*KE, KE, KE, lsA, lsB, acc);
  const int tid=threadIdx.x, wave=tid>>6, lane=tid&63, wm=wave>>1, wn=wave&1;
#pragma unroll
  for (int mi=0;mi<4;mi++)
#pragma unroll
    for (int nj=0;nj<4;nj++)
#pragma unroll
      for (int q=0;q<4;q++){
        int r = m0 + wm*64 + mi*16 + (lane>>4)*4 + q;
        int c = n0 + wn*64 + nj*16 + (lane&15);
        gre[(size_t)r*NW + c] = acc[mi][nj][q];
      }
}

static __device__ __forceinline__ void gemm1_epilogue(float* __restrict__ g, int n0, f32x4 (&acc)[4][4]){
  const int tid=threadIdx.x, wave=tid>>6, lane=tid&63, wm=wave>>1, wn=wave&1;
#pragma unroll
  for (int mi=0;mi<4;mi++)
#pragma unroll
    for (int nj=0;nj<4;nj++)
#pragma unroll
      for (int q=0;q<4;q++){
        int r = wm*64 + mi*16 + (lane>>4)*4 + q;
        int c = n0 + wn*64 + nj*16 + (lane&15);
        g[(size_t)r*N1 + c] = acc[mi][nj][q];
      }
}

__global__ __launch_bounds__(256) void k_gemm1(const u16* __restrict__ x1, const u16* __restrict__ W1, float* __restrict__ g){
  __shared__ __align__(16) u16 lsA[4096], lsB[4096];
  const int n0 = blockIdx.x*128;
  f32x4 acc[4][4];
  gemm_core(x1, K1, W1 + (size_t)n0*K1, K1, K1, lsA, lsB, acc);
  gemm1_epilogue(g, n0, acc);
}

// ---------------- per-step kernels ----------------

// K2': gru-elem (dup) + q for a-half (vectorized Ws rows) + e-partials over a-half. grid 256, 512 thr
__global__ __launch_bounds__(512) void k_gqe(const float* __restrict__ g, const float* __restrict__ gre,
    const float* __restrict__ bih, const float* __restrict__ bhh,
    const float* __restrict__ s_old, float* __restrict__ s_new, u16* __restrict__ x1,
    const u16* __restrict__ Wsb, const float* __restrict__ attb, const float* __restrict__ attv,
    const u16* __restrict__ eproj, float* __restrict__ e_part, int t){
  const int tid = threadIdx.x;
  const int b = blockIdx.x >> 1, y = blockIdx.x & 1;
  __shared__ float s_lds[512];
  __shared__ float q_lds[256];
  const float* gb = g + (size_t)b*N1;
  const float* ge = gre + ((size_t)(t*NB + b))*NW;
  {
    const int j = tid;
    float r = fsig(gb[j] + ge[j] + bih[j] + bhh[j]);
    float z = fsig(gb[512+j] + ge[512+j] + bih[512+j] + bhh[512+j]);
    float n = ftanh(ge[1024+j] + gb[1536+j] + bih[1024+j] + r*(gb[1024+j] + bhh[1024+j]));
    float sn = (1.f-z)*n + z*s_old[(size_t)b*512 + j];
    s_lds[j] = sn;
    if (y==0){ s_new[(size_t)b*512 + j] = sn; x1[(size_t)b*K1 + j] = f2b(sn); }
  }
  __syncthreads();
  {
    // q[a] for a in this block's half; 2 threads per a (k-halves), contiguous bf16x8 loads
    const int a = y*256 + (tid>>1), kh = tid&1;
    const u16* wr = Wsb + (size_t)a*512 + kh*256;
    const float* sp = s_lds + kh*256;
    float acc = 0.f;
#pragma unroll 8
    for (int k=0;k<256;k+=8){
      bf16x8 w = *(const bf16x8*)(wr + k);
#pragma unroll
      for (int j=0;j<8;j++) acc += sp[k+j]*b2f((u16)w[j]);
    }
    acc += __shfl_xor(acc, 1);
    if (kh==0) q_lds[tid>>1] = acc + attb[a];
  }
  __syncthreads();
  const int lane = tid&63, wv = tid>>6;
  float v4[4], q4[4];
#pragma unroll
  for (int j=0;j<4;j++){ v4[j]=attv[y*256 + lane*4 + j]; q4[j]=q_lds[lane*4 + j]; }
  float* ep_out = e_part + ((size_t)y*NB + b)*NL;
#pragma unroll 2
  for (int i=0;i<50;i++){
    const int l = wv + 8*i;
    const u16* ep = eproj + ((size_t)b*NL + l)*512 + y*256 + lane*4;
    const uint2 pk = *(const uint2*)ep;
    float acc = v4[0]*ftanh(b2f((u16)(pk.x&0xFFFFu)) + q4[0]);
    acc += v4[1]*ftanh(b2f((u16)(pk.x>>16)) + q4[1]);
    acc += v4[2]*ftanh(b2f((u16)(pk.y&0xFFFFu)) + q4[2]);
    acc += v4[3]*ftanh(b2f((u16)(pk.y>>16)) + q4[3]);
    for (int off=32; off; off>>=1) acc += __shfl_xor(acc, off);
    if (lane==0) ep_out[l] = acc;
  }
}

// K3': combine e-partials + mask + softmax + ctx (via encT, vectorized) + attn store. grid 256, 512 thr
__global__ __launch_bounds__(512) void k_sm_ctx(const float* __restrict__ e_part, const int* __restrict__ src,
    const u16* __restrict__ encT, float* __restrict__ attn_ws, u16* __restrict__ x1,
    float* __restrict__ ctx_ws){
  const int tid = threadIdx.x;
  const int b = blockIdx.x >> 1, y = blockIdx.x & 1;
  const int lane = tid&63, wv = tid>>6;
  __shared__ float a_lds[NL];
  __shared__ float red[8];
  __shared__ float bc1, bc2;
  float ev = -INFINITY;
  if (tid < NL){
    float e = e_part[(size_t)b*NL + tid] + e_part[((size_t)NB + b)*NL + tid];
    ev = (src[b*NL + tid]==0) ? -INFINITY : e;
  }
  float mx = ev;
  for (int off=32; off; off>>=1) mx = fmaxf(mx, __shfl_xor(mx, off));
  if (lane==0) red[wv]=mx;
  __syncthreads();
  if (tid==0){ float m=red[0]; for(int i=1;i<8;i++) m=fmaxf(m,red[i]); bc1=m; }
  __syncthreads();
  float p = (tid<NL)? __expf(ev - bc1) : 0.f;
  float sm = p;
  for (int off=32; off; off>>=1) sm += __shfl_xor(sm, off);
  if (lane==0) red[wv]=sm;
  __syncthreads();
  if (tid==0){ float s2=0; for(int i=0;i<8;i++) s2+=red[i]; bc2=s2; }
  __syncthreads();
  if (tid<NL){
    float av = p / bc2;
    a_lds[tid] = av;
    if (y==0) attn_ws[(size_t)b*NL + tid] = av;
  }
  __syncthreads();
  // ctx[j] for j in this block's half; 2 threads per j (l-halves), contiguous encT rows
  const int j = y*256 + (tid>>1), lh = tid&1;
  const u16* er = encT + ((size_t)b*512 + j)*NL + lh*200;
  const float* ap = a_lds + lh*200;
  float acc = 0.f;
#pragma unroll 5
  for (int m=0;m<200;m+=8){
    bf16x8 e8 = *(const bf16x8*)(er + m);
#pragma unroll
    for (int jj=0;jj<8;jj++) acc += ap[m+jj]*b2f((u16)e8[jj]);
  }
  acc += __shfl_xor(acc, 1);
  if (lh==0){
    x1[(size_t)b*K1 + 512 + j] = f2b(acc);
    ctx_ws[(size_t)b*512 + j] = acc;
  }
}

// K4: blocks 0..3: read-GEMM + maxout; blocks 4..7: p_copy. grid 8, 256 thr
__global__ __launch_bounds__(256) void k_read_pc(const u16* __restrict__ x1, const u16* __restrict__ W2,
    const float* __restrict__ gre, const float* __restrict__ readb, u16* __restrict__ mbf,
    const float* __restrict__ s_new, const float* __restrict__ ctx_ws,
    const float* __restrict__ copyW, const float* __restrict__ copyb, float* __restrict__ pcb, int t){
  const int bx = blockIdx.x, tid = threadIdx.x;
  if (bx < 4){
    __shared__ __align__(16) u16 lsA[4096], lsB[4096];
    const int n0 = bx*128;
    f32x4 acc[4][4];
    gemm_core(x1, K1, W2 + (size_t)n0*K1, K1, K1, lsA, lsB, acc);
    const int wave=tid>>6, lane=tid&63, wm=wave>>1, wn=wave&1;
#pragma unroll
    for (int mi=0;mi<4;mi++)
#pragma unroll
      for (int nj=0;nj<4;nj++)
#pragma unroll
        for (int q=0;q<4;q++){
          int r = wm*64 + mi*16 + (lane>>4)*4 + q;
          int c = n0 + wn*64 + nj*16 + (lane&15);
          float v = acc[mi][nj][q] + readb[c] + gre[((size_t)(t*NB + r))*NW + 1536 + c];
          float o = __shfl_xor(v, 1);
          float mx2 = fmaxf(v, o);
          if (!(lane&1)) mbf[(size_t)r*256 + (c>>1)] = f2b(mx2);
        }
    return;
  }
  // p_copy: 32 b per block, 8 threads per b
  const int b = (bx-4)*32 + (tid>>3), kq = tid&7;
  const float* v = (kq<4) ? (s_new + (size_t)b*512 + kq*128) : (ctx_ws + (size_t)b*512 + (kq-4)*128);
  const float* w = copyW + kq*128;
  float acc = 0.f;
#pragma unroll 8
  for (int k=0;k<128;k+=4){
    const float4 vv = *(const float4*)(v+k);
    const float4 ww = *(const float4*)(w+k);
    acc += vv.x*ww.x + vv.y*ww.y + vv.z*ww.z + vv.w*ww.w;
  }
  acc += __shfl_xor(acc,1); acc += __shfl_xor(acc,2); acc += __shfl_xor(acc,4);
  if (kq==0) pcb[b] = fsig(acc + copyb[0]);
}

// K5: energy = m @ Wo^T (+ per-row exp-sum partials). grid 157
__global__ __launch_bounds__(256) void k_energy(const u16* __restrict__ mbf, const u16* __restrict__ Wo,
    float* __restrict__ energy, float* __restrict__ parts){
  __shared__ __align__(16) u16 lsA[4096], lsB[4096];
  __shared__ float psum[128][2];
  const int n0 = blockIdx.x*128;
  f32x4 acc[4][4];
  gemm_core(mbf, 256, Wo + (size_t)n0*256, 256, 256, lsA, lsB, acc);
  const int tid=threadIdx.x, wave=tid>>6, lane=tid&63, wm=wave>>1, wn=wave&1;
  float rs[4][4];
#pragma unroll
  for (int mi=0;mi<4;mi++)
#pragma unroll
    for (int q=0;q<4;q++) rs[mi][q]=0.f;
#pragma unroll
  for (int mi=0;mi<4;mi++)
#pragma unroll
    for (int nj=0;nj<4;nj++){
      const int c = n0 + wn*64 + nj*16 + (lane&15);
#pragma unroll
      for (int q=0;q<4;q++){
        const int r = wm*64 + mi*16 + (lane>>4)*4 + q;
        float e = acc[mi][nj][q];
        if (c < NV){ energy[(size_t)r*NV + c] = e; rs[mi][q] += __expf(e); }
      }
    }
#pragma unroll
  for (int mi=0;mi<4;mi++)
#pragma unroll
    for (int q=0;q<4;q++){
      float v = rs[mi][q];
      v += __shfl_xor(v,1); v += __shfl_xor(v,2); v += __shfl_xor(v,4); v += __shfl_xor(v,8);
      if ((lane&15)==0) psum[wm*64 + mi*16 + (lane>>4)*4 + q][wn] = v;
    }
  __syncthreads();
  if (tid < 128) parts[(size_t)tid*160 + blockIdx.x] = psum[tid][0] + psum[tid][1];
}

// K6: vocab log-probs + copy-slice out for step t + gemm1 for step t+1. grid 272
__global__ __launch_bounds__(256) void k_outg(const float* __restrict__ energy, const float* __restrict__ parts,
    const float* __restrict__ pcb, const float* __restrict__ attn_ws, float* __restrict__ out, int t,
    const u16* __restrict__ x1, const u16* __restrict__ W1, float* __restrict__ g, int do_g){
  __shared__ __align__(16) u16 lsA[4096], lsB[4096];
  const int bx = blockIdx.x, tid = threadIdx.x;
  if (bx >= 256){
    if (!do_g) return;
    const int n0 = (bx-256)*128;
    f32x4 acc[4][4];
    gemm_core(x1, K1, W1 + (size_t)n0*K1, K1, K1, lsA, lsB, acc);
    gemm1_epilogue(g, n0, acc);
    return;
  }
  const int b = bx>>1, half = bx&1;
  const int lane = tid&63, wv = tid>>6;
  __shared__ float red[4];
  __shared__ float bcL, bcO, bcP;
  float v = (tid<157)? parts[(size_t)b*160 + tid] : 0.f;
  for (int off=32; off; off>>=1) v += __shfl_xor(v, off);
  if (lane==0) red[wv]=v;
  __syncthreads();
  if (tid==0){ bcL = __logf(red[0]+red[1]+red[2]+red[3]); float pc = pcb[b]; bcO = 1.f - pc; bcP = pc; }
  __syncthreads();
  const float LSE = bcL, omp = bcO, pcv = bcP;
  float* orow = out + ((size_t)b*NT + t)*OUTW;
  const float* eb = energy + (size_t)b*NV + half*10000;
  float* ob = orow + half*10000;
  for (int i=tid; i<10000; i+=256) ob[i] = __logf(omp*__expf(eb[i]-LSE) + 1e-12f);
  if (half==0){
    const float* aw = attn_ws + (size_t)b*NL;
    for (int i=tid; i<NL; i+=256) orow[NV + i] = __logf(pcv*aw[i] + 1e-12f);
  }
}

// ---------------- launch ----------------

extern "C" void kernel_launch(void* const* d_in, const int* in_sizes, int n_in,
                              void* d_out, int out_size, void* d_ws, size_t ws_size,
                              hipStream_t stream){
  const float* enc   = (const float*)d_in[0];
  const float* s_in  = (const float*)d_in[1];
  const int*   src   = (const int*)d_in[2];
  const int*   tgt   = (const int*)d_in[3];
  const float* embed = (const float*)d_in[4];
  const float* W_ih  = (const float*)d_in[5];
  const float* b_ih  = (const float*)d_in[6];
  const float* W_hh  = (const float*)d_in[7];
  const float* b_hh  = (const float*)d_in[8];
  const float* attWh = (const float*)d_in[9];
  const float* attWs = (const float*)d_in[10];
  const float* attb  = (const float*)d_in[11];
  const float* attv  = (const float*)d_in[12];
  const float* copyW = (const float*)d_in[13];
  const float* copyb = (const float*)d_in[14];
  const float* readW = (const float*)d_in[15];
  const float* readb = (const float*)d_in[16];
  const float* readWo= (const float*)d_in[17];
  float* out = (float*)d_out;
  (void)in_sizes; (void)n_in; (void)out_size; (void)ws_size;

  char* wsp = (char*)d_ws;
  size_t off = 0;
  auto alloc = [&](size_t bytes)->char*{ char* p = wsp + off; off = (off + bytes + 255) & ~(size_t)255; return p; };
  u16* enc_bf   = (u16*)alloc((size_t)NB*NL*NHE*2);
  u16* encT     = (u16*)alloc((size_t)NB*NHE*NL*2);
  u16* eproj    = (u16*)alloc((size_t)NB*NL*NA*2);
  u16* attWh_bf = (u16*)alloc((size_t)NA*NHE*2);
  u16* Wsb      = (u16*)alloc((size_t)NA*NHD*2);
  u16* W1       = (u16*)alloc((size_t)N1*K1*2);
  u16* W2       = (u16*)alloc((size_t)512*K1*2);
  u16* Wemb     = (u16*)alloc((size_t)NW*KE*2);
  u16* Xemb     = (u16*)alloc((size_t)NT*NB*KE*2);
  u16* WoP      = (u16*)alloc((size_t)NVP*256*2);
  float* gre    = (float*)alloc((size_t)NT*NB*NW*4);
  float* g      = (float*)alloc((size_t)NB*N1*4);
  u16* x1       = (u16*)alloc((size_t)NB*K1*2);
  float* sbufA  = (float*)alloc((size_t)NB*NHD*4);
  float* sbufB  = (float*)alloc((size_t)NB*NHD*4);
  float* e_part = (float*)alloc((size_t)2*NB*NL*4);
  float* attn_ws= (float*)alloc((size_t)NB*NL*4);
  float* ctx_ws = (float*)alloc((size_t)NB*NHE*4);
  u16* mbf      = (u16*)alloc((size_t)NB*256*2);
  float* energy = (float*)alloc((size_t)NB*NV*4);
  float* parts  = (float*)alloc((size_t)NB*160*4);
  float* pcb    = (float*)alloc((size_t)NB*4);

  k_conv_flat<<<4096,256,0,stream>>>(enc, enc_bf, (long)NB*NL*NHE);
  k_transpose<<<dim3(16,128),512,0,stream>>>(enc, encT);
  k_conv_flat<<<1024,256,0,stream>>>(attWh, attWh_bf, (long)NA*NHE);
  k_conv_flat<<<1024,256,0,stream>>>(attWs, Wsb, (long)NA*NHD);
  k_build_w1<<<8192,256,0,stream>>>(W_hh, W_ih, W1);
  k_build_w2<<<2048,256,0,stream>>>(readW, W2);
  k_build_wemb<<<2560,256,0,stream>>>(W_ih, readW, Wemb);
  k_build_xemb<<<4800,256,0,stream>>>(tgt, embed, Xemb);
  k_convpad<<<2048,256,0,stream>>>(readWo, WoP, NV, 256, 256, (long)NVP*256);
  k_init<<<512,256,0,stream>>>(s_in, sbufA, x1);
  k_encproj<<<dim3(4,400),256,0,stream>>>(enc_bf, attWh_bf, eproj);
  k_gemm_emb<<<dim3(16,30),256,0,stream>>>(Xemb, Wemb, gre);
  k_gemm1<<<16,256,0,stream>>>(x1, W1, g);

  for (int t=0; t<NT; t++){
    const float* s_old = (t&1) ? sbufB : sbufA;
    float* s_new       = (t&1) ? sbufA : sbufB;
    k_gqe<<<256,512,0,stream>>>(g, gre, b_ih, b_hh, s_old, s_new, x1, Wsb, attb, attv,
                                eproj, e_part, t);
    k_sm_ctx<<<256,512,0,stream>>>(e_part, src, encT, attn_ws, x1, ctx_ws);
    k_read_pc<<<8,256,0,stream>>>(x1, W2, gre, readb, mbf, s_new, ctx_ws, copyW, copyb, pcb, t);
    k_energy<<<157,256,0,stream>>>(mbf, WoP, energy, parts);
    k_outg<<<272,256,0,stream>>>(energy, parts, pcb, attn_ws, out, t, x1, W1, g, (t+1<NT) ? 1 : 0);
  }
}